// Round 6
// baseline (432.766 us; speedup 1.0000x reference)
//
#include <hip/hip_runtime.h>
#include <hip/hip_bf16.h>
#include <math.h>

#define DIMK 1024
#define NH 16
#define HD 64
#define BB 4
#define SS 8192
#define EPAD 136
#define NT 96  // K' = 3072 / BK=32

typedef __attribute__((ext_vector_type(8))) short bf16x8;
typedef __attribute__((ext_vector_type(8))) unsigned short ushort8;
typedef __attribute__((ext_vector_type(4))) unsigned short us4;
typedef __attribute__((ext_vector_type(4))) float f32x4;

#define MFMA16(a, b, c) __builtin_amdgcn_mfma_f32_16x16x32_bf16((a), (b), (c), 0, 0, 0)

__device__ __forceinline__ unsigned short f32_to_bf16_rne(float f) {
  unsigned int u = __float_as_uint(f);
  u = (u + 0x7fffu + ((u >> 16) & 1u)) >> 16;
  return (unsigned short)u;
}
__device__ __forceinline__ float bf16_bits_to_f32(unsigned short b) {
  return __uint_as_float(((unsigned int)b) << 16);
}
__device__ __forceinline__ void gload16(const void* g, void* l) {
  __builtin_amdgcn_global_load_lds((const __attribute__((address_space(1))) void*)g,
                                   (__attribute__((address_space(3))) void*)l, 16, 0, 0);
}

// ---------------- fill d_out with bo broadcast ----------------
__global__ __launch_bounds__(256) void fill_out_kernel(const float4* __restrict__ bo4,
                                                       float4* __restrict__ out, int total4) {
  for (int i = blockIdx.x * 256 + threadIdx.x; i < total4; i += gridDim.x * 256)
    out[i] = bo4[i & 255];
}

// ---------------- W [k][n] fp32 -> tiled+swizzled bf16 hi/lo panels ----------------
// B layout: panel p = pn*64 + kt (hi) / pn*64+32+kt (lo); panel = [128 n-rows][32 k] 8KB,
// chunk swizzle q' = q ^ ((r>>1)&3).
__global__ __launch_bounds__(256) void prep_w(const float* __restrict__ W,
                                              unsigned short* __restrict__ Bpan, int pnoff) {
  __shared__ float st[64][65];
  const int bk = blockIdx.x * 64, bn = blockIdx.y * 64;
  const int t = threadIdx.x;
  const int lr = t >> 4, lc = (t & 15) * 4;
#pragma unroll
  for (int i = 0; i < 4; i++) {
    int k = lr + i * 16;
    float4 v = *(const float4*)(W + (size_t)(bk + k) * DIMK + bn + lc);
    st[k][lc] = v.x; st[k][lc + 1] = v.y; st[k][lc + 2] = v.z; st[k][lc + 3] = v.w;
  }
  __syncthreads();
  const int ktile = (bk + lc) >> 5, c = lc & 31;
#pragma unroll
  for (int i = 0; i < 4; i++) {
    const int nl = lr + i * 16;
    const int n = bn + nl;
    const int r = n & 127, pn = (n >> 7) + pnoff;
    const int q = (c >> 3) ^ ((r >> 1) & 3);
    const size_t byteoff = (size_t)r * 64 + q * 16 + (c & 7) * 2;
    us4 hv, lv;
#pragma unroll
    for (int j = 0; j < 4; j++) {
      float v = st[lc + j][nl];
      unsigned short hb = f32_to_bf16_rne(v);
      hv[j] = hb;
      lv[j] = f32_to_bf16_rne(v - bf16_bits_to_f32(hb));
    }
    char* base = (char*)Bpan;
    *(us4*)(base + (((size_t)pn * 64 + ktile) << 13) + byteoff) = hv;
    *(us4*)(base + (((size_t)pn * 64 + 32 + ktile) << 13) + byteoff) = lv;
  }
}

// ---------------- split W1 [128][64] fp32 -> W1T hi/lo [64][128] bf16 ----------------
__global__ __launch_bounds__(256) void prep_w1(const float* __restrict__ W1,
                                               unsigned short* __restrict__ W1Th,
                                               unsigned short* __restrict__ W1Tl) {
  for (int idx = threadIdx.x; idx < 128 * 64; idx += 256) {
    int k = idx >> 6, n = idx & 63;
    float v = W1[idx];
    unsigned short hb = f32_to_bf16_rne(v);
    W1Th[n * 128 + k] = hb;
    W1Tl[n * 128 + k] = f32_to_bf16_rne(v - bf16_bits_to_f32(hb));
  }
}

// ---------------- gather rows of X -> tiled+swizzled bf16 hi/lo A panels ----------------
// A layout: panel p = mt*64 + kt (hi) / mt*64+32+kt (lo); panel = [256 rows][32 k] 16KB.
__global__ __launch_bounds__(256) void prep_a(const float* __restrict__ X,
                                              const int* __restrict__ gidx,
                                              unsigned short* __restrict__ Apan, int M, int E) {
  const int row = blockIdx.x;  // < Mpad
  const int r = row & 255, mt = row >> 8;
  const int c0 = threadIdx.x * 4;
  const int kt = c0 >> 5, c = c0 & 31;
  const int q = (c >> 3) ^ ((r >> 1) & 3);
  const size_t byteoff = (size_t)r * 64 + q * 16 + (c & 7) * 2;
  char* base = (char*)Apan;
  us4 hv = (us4){0, 0, 0, 0}, lv = (us4){0, 0, 0, 0};
  if (row < M) {
    const float* sr;
    if (gidx) {
      int b = row / E, e = row - b * E;
      sr = X + ((size_t)b * SS + gidx[e]) * DIMK;
    } else {
      sr = X + (size_t)row * DIMK;
    }
    float4 v = *(const float4*)(sr + c0);
    float vv[4] = {v.x, v.y, v.z, v.w};
#pragma unroll
    for (int i = 0; i < 4; i++) {
      unsigned short hb = f32_to_bf16_rne(vv[i]);
      hv[i] = hb;
      lv[i] = f32_to_bf16_rne(vv[i] - bf16_bits_to_f32(hb));
    }
  }
  *(us4*)(base + (((size_t)(mt * 64 + kt)) << 14) + byteoff) = hv;
  *(us4*)(base + (((size_t)(mt * 64 + 32 + kt)) << 14) + byteoff) = lv;
}

// ---------------- first-occurrence map via atomicMin table ----------------
__global__ __launch_bounds__(256) void init_table(int* __restrict__ t) {
  t[blockIdx.x * 256 + threadIdx.x] = 0x7fffffff;
}
__global__ __launch_bounds__(256) void build_first(const int* __restrict__ src,
                                                   int* __restrict__ t, int E) {
  int e = blockIdx.x * 256 + threadIdx.x;
  if (e < E) atomicMin(&t[src[e]], e);
}
__global__ __launch_bounds__(256) void read_first(const int* __restrict__ src,
                                                  const int* __restrict__ t,
                                                  int* __restrict__ f, int E) {
  int e = blockIdx.x * 256 + threadIdx.x;
  if (e < E) f[e] = t[src[e]];
}

// ---------------- deep-pipelined K-concat bf16 GEMM ----------------
// C[M][N] = A'(K'=3072) @ B'. 256xBN tile, BK=32, 8 waves, 4 LDS buffers,
// counted vmcnt (never drain in steady state), global_load_lds w16, swizzled panels.
// MODE 0: out[m*ldc + n] = acc + bias_sel(n)
// MODE 1: out[(b*SS+srci[e])*ldc + n] = acc + bias[n] iff fidx[e]==e
template <int BN, int MODE>
__global__ __launch_bounds__(512, 2) void gemm8(
    const unsigned short* __restrict__ Apan, const unsigned short* __restrict__ Bpan,
    const float* __restrict__ bias, const float* __restrict__ bias2,
    float* __restrict__ out, int ldc, int nty,
    const int* __restrict__ fidx, const int* __restrict__ srci, int M, int E) {
  constexpr int NF = BN / 64;           // B frags per wave
  constexpr int BTILE = BN * 32;        // ushorts per B tile
  __shared__ unsigned short ldsA[4][8192];
  __shared__ unsigned short ldsB[4][BTILE];

  const int tid = threadIdx.x, lane = tid & 63, wv = tid >> 6;
  const int wr = wv >> 2, wc = wv & 3;

  // XCD-aware block swizzle (grid % 8 == 0)
  const int w = (blockIdx.x & 7) * ((int)gridDim.x >> 3) + ((int)blockIdx.x >> 3);
  const int mt = w / nty, nt_ = w - mt * nty;
  const int m0 = mt * 256, n0 = nt_ * BN;

  const int rr = lane & 15, lq = lane >> 4;
  const int swz = (rr >> 1) & 3;
  const int aoff = (wr * 128 + rr) * 32 + ((lq ^ swz) << 3);         // + mf*512
  const int boff = (wc * (BN / 4) + rr) * 32 + ((lq ^ swz) << 3);    // + nf*512

  const char* Apb = (const char*)Apan + ((size_t)(mt * 64) << 14);
  const char* Bpb = (const char*)Bpan;
  const int stoff = wv * 1024 + lane * 16;  // byte offset of this thread in an 8KB half

  f32x4 acc[8][NF];
#pragma unroll
  for (int i = 0; i < 8; i++)
#pragma unroll
    for (int j = 0; j < NF; j++) acc[i][j] = (f32x4){0.f, 0.f, 0.f, 0.f};

  auto stageA = [&](int kt, int buf) {
    const int apk = kt < 64 ? kt : kt - 64;
    const char* s = Apb + ((size_t)apk << 14) + stoff;
    gload16(s, &ldsA[buf][wv * 512]);
    gload16(s + 8192, &ldsA[buf][wv * 512 + 4096]);
  };
  auto stageB = [&](int kt, int buf) {
    const int bpk = kt < 32 ? kt : kt - 32;
    if (BN == 256) {
      const char* s0 = Bpb + (((size_t)(2 * nt_) * 64 + bpk) << 13) + stoff;
      const char* s1 = Bpb + (((size_t)(2 * nt_ + 1) * 64 + bpk) << 13) + stoff;
      gload16(s0, &ldsB[buf][wv * 512]);
      gload16(s1, &ldsB[buf][wv * 512 + 4096]);
    } else {
      const char* s0 = Bpb + (((size_t)nt_ * 64 + bpk) << 13) + stoff;
      gload16(s0, &ldsB[buf][wv * 512]);
    }
  };

  // prologue: stage tiles 0,1,2; require tile 0 landed (allow 2 tiles outstanding)
  stageA(0, 0); stageB(0, 0);
  stageA(1, 1); stageB(1, 1);
  stageA(2, 2); stageB(2, 2);
  if constexpr (BN == 256) asm volatile("s_waitcnt vmcnt(8)" ::: "memory");
  else asm volatile("s_waitcnt vmcnt(6)" ::: "memory");
  __builtin_amdgcn_sched_barrier(0);
  __builtin_amdgcn_s_barrier();

  for (int kt = 0; kt < NT; ++kt) {
    const int buf = kt & 3;
    const unsigned short* Al = ldsA[buf];
    const unsigned short* Bl = ldsB[buf];
    const int sb = (kt + 3) & 3;
    const bool st = (kt + 3 < NT);

    // phase 0: B frags + A frags mf0-3; issue A stage; MFMA mf0-3
    bf16x8 fb[NF];
#pragma unroll
    for (int nf = 0; nf < NF; ++nf) fb[nf] = *(const bf16x8*)(Bl + boff + nf * 512);
    bf16x8 fa[4];
#pragma unroll
    for (int mf = 0; mf < 4; ++mf) fa[mf] = *(const bf16x8*)(Al + aoff + mf * 512);
    if (st) stageA(kt + 3, sb);
#pragma unroll
    for (int mf = 0; mf < 4; ++mf)
#pragma unroll
      for (int nf = 0; nf < NF; ++nf) acc[mf][nf] = MFMA16(fa[mf], fb[nf], acc[mf][nf]);

    // phase 1: A frags mf4-7; issue B stage; MFMA mf4-7
    bf16x8 fa2[4];
#pragma unroll
    for (int mf = 0; mf < 4; ++mf) fa2[mf] = *(const bf16x8*)(Al + aoff + (mf + 4) * 512);
    if (st) stageB(kt + 3, sb);
#pragma unroll
    for (int mf = 0; mf < 4; ++mf)
#pragma unroll
      for (int nf = 0; nf < NF; ++nf) acc[mf + 4][nf] = MFMA16(fa2[mf], fb[nf], acc[mf + 4][nf]);

    // tile boundary: counted wait (t+1 landed), raw barrier (no vmcnt drain)
    if (kt < NT - 1) {
      if (kt + 3 < NT) {
        if constexpr (BN == 256) asm volatile("s_waitcnt vmcnt(8)" ::: "memory");
        else asm volatile("s_waitcnt vmcnt(6)" ::: "memory");
      } else if (kt + 2 < NT) {
        if constexpr (BN == 256) asm volatile("s_waitcnt vmcnt(4)" ::: "memory");
        else asm volatile("s_waitcnt vmcnt(3)" ::: "memory");
      } else {
        asm volatile("s_waitcnt vmcnt(0)" ::: "memory");
      }
      __builtin_amdgcn_sched_barrier(0);
      __builtin_amdgcn_s_barrier();
    }
  }

  // epilogue: C layout col=lane&15, row=(lane>>4)*4+r (same convention as verified R2 kernel)
  const int cq = lane >> 4, cr = lane & 15;
#pragma unroll
  for (int nf = 0; nf < NF; ++nf) {
    const int col = n0 + wc * (BN / 4) + nf * 16 + cr;
    const float bv = (MODE == 0 && bias2 != nullptr && col >= DIMK) ? bias2[col - DIMK]
                                                                    : bias[col & (DIMK - 1)];
#pragma unroll
    for (int mf = 0; mf < 8; ++mf) {
#pragma unroll
      for (int r = 0; r < 4; ++r) {
        const int mrow = m0 + wr * 128 + mf * 16 + cq * 4 + r;
        if (mrow >= M) continue;
        if (MODE == 0) {
          out[(size_t)mrow * ldc + col] = acc[mf][nf][r] + bv;
        } else {
          int b = mrow / E, e = mrow - b * E;
          if (fidx[e] == e) {
            int orow = b * SS + srci[e];
            out[(size_t)orow * ldc + col] = acc[mf][nf][r] + bv;
          }
        }
      }
    }
  }
}

// ---------------- edge MLP scores via MFMA ----------------
__global__ __launch_bounds__(256) void edge_scores_mfma(
    const float* __restrict__ qs, const float* __restrict__ kd, int ldk,
    const unsigned short* __restrict__ W1Th, const unsigned short* __restrict__ W1Tl,
    const float* __restrict__ b1, const float* __restrict__ W2,
    const float* __restrict__ b2, float* __restrict__ scores, int E, int CH) {
  __shared__ unsigned short W1h[64][EPAD], W1l[64][EPAD];
  __shared__ unsigned short EFh[4][16][EPAD], EFl[4][16][EPAD];
  const int tid = threadIdx.x, lane = tid & 63, w = tid >> 6;
  const int bh = blockIdx.x / CH, ch = blockIdx.x - bh * CH;
  const int b = bh >> 4, h = bh & 15;

  for (int idx = tid; idx < 64 * 16; idx += 256) {
    int n = idx >> 4, g = (idx & 15) * 8;
    *(ushort8*)&W1h[n][g] = *(const ushort8*)(W1Th + n * 128 + g);
    *(ushort8*)&W1l[n][g] = *(const ushort8*)(W1Tl + n * 128 + g);
  }
  __syncthreads();

  const int etile = ch * 4 + w;
  const int e0 = etile * 16;
  if (e0 >= E) return;

  const int r = lane >> 2, c0 = (lane & 3) * 16;
  {
    const int er = (e0 + r < E) ? e0 + r : E - 1;
    const float* qrow = qs + ((size_t)(b * E + er)) * DIMK + h * HD + c0;
    const float* krow = kd + ((size_t)(b * E + er)) * (size_t)ldk + h * HD + c0;
    float qv[16], kvv[16];
#pragma unroll
    for (int i = 0; i < 4; i++) {
      *(float4*)&qv[i * 4] = *(const float4*)(qrow + i * 4);
      *(float4*)&kvv[i * 4] = *(const float4*)(krow + i * 4);
    }
    ushort8 qh[2], ql[2], kh[2], kl[2];
#pragma unroll
    for (int g = 0; g < 2; g++)
#pragma unroll
      for (int i = 0; i < 8; i++) {
        float v = qv[g * 8 + i];
        unsigned short hb = f32_to_bf16_rne(v);
        qh[g][i] = hb;
        ql[g][i] = f32_to_bf16_rne(v - bf16_bits_to_f32(hb));
        float v2 = kvv[g * 8 + i];
        unsigned short hb2 = f32_to_bf16_rne(v2);
        kh[g][i] = hb2;
        kl[g][i] = f32_to_bf16_rne(v2 - bf16_bits_to_f32(hb2));
      }
    *(ushort8*)&EFh[w][r][c0] = qh[0];
    *(ushort8*)&EFh[w][r][c0 + 8] = qh[1];
    *(ushort8*)&EFl[w][r][c0] = ql[0];
    *(ushort8*)&EFl[w][r][c0 + 8] = ql[1];
    *(ushort8*)&EFh[w][r][64 + c0] = kh[0];
    *(ushort8*)&EFh[w][r][64 + c0 + 8] = kh[1];
    *(ushort8*)&EFl[w][r][64 + c0] = kl[0];
    *(ushort8*)&EFl[w][r][64 + c0 + 8] = kl[1];
  }
  asm volatile("s_waitcnt lgkmcnt(0)" ::: "memory");
  __builtin_amdgcn_sched_barrier(0);

  f32x4 acc[4];
#pragma unroll
  for (int i = 0; i < 4; i++) acc[i] = (f32x4){0.f, 0.f, 0.f, 0.f};

  const int kk = (lane >> 4) * 8, rrl = lane & 15;
#pragma unroll
  for (int ks = 0; ks < 4; ks++) {
    bf16x8 ah = *(bf16x8*)&EFh[w][rrl][ks * 32 + kk];
    bf16x8 al = *(bf16x8*)&EFl[w][rrl][ks * 32 + kk];
#pragma unroll
    for (int nf = 0; nf < 4; nf++) {
      bf16x8 bh_ = *(bf16x8*)&W1h[nf * 16 + rrl][ks * 32 + kk];
      bf16x8 bl_ = *(bf16x8*)&W1l[nf * 16 + rrl][ks * 32 + kk];
      acc[nf] = MFMA16(ah, bh_, acc[nf]);
      acc[nf] = MFMA16(ah, bl_, acc[nf]);
      acc[nf] = MFMA16(al, bh_, acc[nf]);
    }
  }

  const int col_l = lane & 15, rq = lane >> 4;
  float w2v[4], b1v[4];
#pragma unroll
  for (int nf = 0; nf < 4; nf++) {
    w2v[nf] = W2[nf * 16 + col_l];
    b1v[nf] = b1[nf * 16 + col_l];
  }
  float p[4];
#pragma unroll
  for (int rr2 = 0; rr2 < 4; rr2++) {
    float s = 0.f;
#pragma unroll
    for (int nf = 0; nf < 4; nf++) {
      float hv = acc[nf][rr2] + b1v[nf];
      hv = 0.5f * hv * (1.f + erff(hv * 0.70710678118654752f));
      s = fmaf(hv, w2v[nf], s);
    }
    p[rr2] = s;
  }
#pragma unroll
  for (int off = 1; off < 16; off <<= 1)
#pragma unroll
    for (int rr2 = 0; rr2 < 4; rr2++) p[rr2] += __shfl_xor(p[rr2], off, 64);

  if (col_l == 0) {
    const float b2v = b2[0];
#pragma unroll
    for (int rr2 = 0; rr2 < 4; rr2++) {
      int e = e0 + rq * 4 + rr2;
      if (e < E) scores[(size_t)(b * NH + h) * E + e] = (p[rr2] + b2v) * 0.125f;
    }
  }
}

// ---------------- softmax over E per (b,h), then *= edge_weight[h] ----------------
__global__ __launch_bounds__(256) void softmax_ew(float* __restrict__ scores,
                                                  const float* __restrict__ ew, int E) {
  const int row = blockIdx.x;
  const int h = row & (NH - 1);
  float* s = scores + (size_t)row * E;
  const int tid = threadIdx.x, lane = tid & 63, w = tid >> 6;
  __shared__ float red[4];

  float vals[8];
  float mx = -1e30f;
#pragma unroll
  for (int i = 0; i < 8; i++) {
    int j = tid + i * 256;
    vals[i] = (j < E) ? s[j] : -1e30f;
    mx = fmaxf(mx, vals[i]);
  }
#pragma unroll
  for (int off = 32; off; off >>= 1) mx = fmaxf(mx, __shfl_xor(mx, off, 64));
  if (lane == 0) red[w] = mx;
  __syncthreads();
  mx = fmaxf(fmaxf(red[0], red[1]), fmaxf(red[2], red[3]));
  __syncthreads();

  float sum = 0.f;
#pragma unroll
  for (int i = 0; i < 8; i++) {
    vals[i] = __expf(vals[i] - mx);
    if (tid + i * 256 < E) sum += vals[i];
  }
#pragma unroll
  for (int off = 32; off; off >>= 1) sum += __shfl_xor(sum, off, 64);
  if (lane == 0) red[w] = sum;
  __syncthreads();
  sum = red[0] + red[1] + red[2] + red[3];

  const float scaleout = ew[h] / sum;
#pragma unroll
  for (int i = 0; i < 8; i++) {
    int j = tid + i * 256;
    if (j < E) s[j] = vals[i] * scaleout;
  }
}

// ---------------- wrow[b*E+e][d] = attn[b,h(d),e] * vd[(b*E+e)*ldv + d] ----------------
__global__ __launch_bounds__(256) void weight_rows(const float* __restrict__ vd, int ldv,
                                                   const float* __restrict__ attn,
                                                   float* __restrict__ wrow, int E) {
  const int row = blockIdx.x;
  const int b = row / E, e = row - b * E;
  const int d = threadIdx.x * 4;
  const int h = d >> 6;
  const float a = attn[(size_t)(b * NH + h) * E + e];
  float4 v = *(const float4*)(vd + (size_t)row * ldv + d);
  v.x *= a; v.y *= a; v.z *= a; v.w *= a;
  *(float4*)(wrow + (size_t)row * DIMK + d) = v;
}

// ---------------- fold duplicate-src edges into primary edge rows ----------------
__global__ __launch_bounds__(256) void dup_add(const int* __restrict__ f,
                                               float* __restrict__ wrow, int E) {
  const int e = blockIdx.x;
  const int fe = f[e];
  if (fe == e) return;
  const int d = threadIdx.x * 4;
#pragma unroll
  for (int b = 0; b < BB; b++) {
    const float4 v = *(const float4*)(wrow + (size_t)(b * E + e) * DIMK + d);
    float* dst = wrow + (size_t)(b * E + fe) * DIMK + d;
    atomicAdd(dst + 0, v.x);
    atomicAdd(dst + 1, v.y);
    atomicAdd(dst + 2, v.z);
    atomicAdd(dst + 3, v.w);
  }
}

extern "C" void kernel_launch(void* const* d_in, const int* in_sizes, int n_in,
                              void* d_out, int out_size, void* d_ws, size_t ws_size,
                              hipStream_t stream) {
  const float* x = (const float*)d_in[0];
  const int* src = (const int*)d_in[1];
  const int* dst = (const int*)d_in[2];
  const float* Wq = (const float*)d_in[3];
  const float* bq = (const float*)d_in[4];
  const float* Wk = (const float*)d_in[5];
  const float* bk = (const float*)d_in[6];
  const float* Wv = (const float*)d_in[7];
  const float* bv = (const float*)d_in[8];
  const float* Wo = (const float*)d_in[9];
  const float* bo = (const float*)d_in[10];
  const float* ew = (const float*)d_in[11];
  const float* W1 = (const float*)d_in[12];
  const float* b1 = (const float*)d_in[13];
  const float* W2 = (const float*)d_in[14];
  const float* b2 = (const float*)d_in[15];
  float* out = (float*)d_out;

  const int E = in_sizes[1];
  const int M = BB * E;
  const int gx = (M + 255) / 256;  // m-tiles
  const int Mpad = gx * 256;

  char* w = (char*)d_ws;
  float* qs = (float*)w; w += (size_t)M * DIMK * 4;
  float* kv = (float*)w; w += (size_t)M * 2048 * 4;
  float* sc = (float*)w; w += (size_t)BB * NH * E * 4;
  int* table = (int*)w; w += (size_t)SS * 4;
  int* fidx = (int*)w; w += (((size_t)E * 4) + 255) & ~(size_t)255;
  unsigned short* W1Th = (unsigned short*)w; w += 64 * 128 * 2;
  unsigned short* W1Tl = (unsigned short*)w; w += 64 * 128 * 2;
  unsigned short* Bq = (unsigned short*)w; w += (size_t)8 * 64 * 8192;    // 4.2 MB
  unsigned short* Bkv = (unsigned short*)w; w += (size_t)16 * 64 * 8192;  // 8.4 MB
  unsigned short* Bo = (unsigned short*)w; w += (size_t)8 * 64 * 8192;    // 4.2 MB
  unsigned short* Apan = (unsigned short*)w; w += (size_t)gx * 64 * 16384;  // 33.5 MB

  float* wrow = qs;  // qs dead after edge_scores

  // 1) fill output with bo
  const int total4 = BB * SS * (DIMK / 4);
  fill_out_kernel<<<2048, 256, 0, stream>>>((const float4*)bo, (float4*)out, total4);

  // 2) weight prep into tiled+swizzled panels; Wk->pn 0-7, Wv->pn 8-15 of Bkv
  dim3 gw(16, 16);
  prep_w<<<gw, 256, 0, stream>>>(Wq, Bq, 0);
  prep_w<<<gw, 256, 0, stream>>>(Wk, Bkv, 0);
  prep_w<<<gw, 256, 0, stream>>>(Wv, Bkv, 8);
  prep_w<<<gw, 256, 0, stream>>>(Wo, Bo, 0);
  prep_w1<<<1, 256, 0, stream>>>(W1, W1Th, W1Tl);

  // 3) first-occurrence map
  init_table<<<SS / 256, 256, 0, stream>>>(table);
  build_first<<<(E + 255) / 256, 256, 0, stream>>>(src, table, E);
  read_first<<<(E + 255) / 256, 256, 0, stream>>>(src, table, fidx, E);

  // 4) q projection (src gather): BN=128, nty = 1024/128 = 8
  prep_a<<<Mpad, 256, 0, stream>>>(x, src, Apan, M, E);
  gemm8<128, 0><<<gx * 8, 512, 0, stream>>>(Apan, Bq, bq, nullptr, qs, DIMK, 8,
                                            nullptr, nullptr, M, E);

  // 5) fused k|v projection (dst gather): BN=256, nty = 2048/256 = 8
  prep_a<<<Mpad, 256, 0, stream>>>(x, dst, Apan, M, E);
  gemm8<256, 0><<<gx * 8, 512, 0, stream>>>(Apan, Bkv, bk, bv, kv, 2048, 8,
                                            nullptr, nullptr, M, E);

  // 6) edge MLP -> scores (k at kv offset 0, stride 2048)
  const int etiles = (E + 15) / 16;
  const int CH = (etiles + 3) / 4;
  edge_scores_mfma<<<BB * NH * CH, 256, 0, stream>>>(qs, kv, 2048, W1Th, W1Tl, b1, W2, b2,
                                                     sc, E, CH);

  // 7) softmax over edges + edge_weight
  softmax_ew<<<BB * NH, 256, 0, stream>>>(sc, ew, E);

  // 8) weighted rows (v at kv offset 1024), fold duplicates, re-split
  weight_rows<<<M, 256, 0, stream>>>(kv + 1024, 2048, sc, wrow, E);
  dup_add<<<E, 256, 0, stream>>>(fidx, wrow, E);
  prep_a<<<Mpad, 256, 0, stream>>>(wrow, nullptr, Apan, M, E);

  // 9) final GEMM: wrow @ Wo, guarded scatter-store
  gemm8<128, 1><<<gx * 8, 512, 0, stream>>>(Apan, Bo, bo, nullptr, out, DIMK, 8,
                                            fidx, src, M, E);
}